// Round 12
// baseline (109.932 us; speedup 1.0000x reference)
//
#include <hip/hip_runtime.h>

constexpr int N_NODES = 10000;
constexpr int N_EDGES = 640000;
constexpr int D       = 128;    // D_IN == D_OUT == 128
constexpr int NBIN1   = 40;     // coarse bin = dst >> 8  (256 nodes)
constexpr int NGRP    = 8;      // cursor groups (blockIdx & 7)
constexpr int CAP1    = 2432;   // per (bin,grp) segment cap: E~2048, +8.5 sigma
constexpr int NSUB    = 625;    // subbin = dst >> 4  (16 nodes)
constexpr int CAP_N   = 130;    // per-node LDS staging cap (Poisson(64) + 8 sigma)
constexpr int GEMM_BLOCKS = 313;
constexpr int PART_BLOCKS = 625;

// workspace layout (bytes)
constexpr size_t WS_BC1    = 0;         // int[40*8*16] = 20480
constexpr size_t WS_WBF    = 24576;     // bf16[128*128] = 32768
constexpr size_t WS_BINNED = 65536;     // int2[320*2432] = 6225920
constexpr size_t WS_YBF    = 6291456;   // bf16[10000*128] = 2560000

typedef __attribute__((ext_vector_type(8))) short bf16x8;
typedef __attribute__((ext_vector_type(4))) short s16x4;
typedef __attribute__((ext_vector_type(4))) float f32x4;

__device__ inline unsigned short f2bf(float f) {   // round-to-nearest-even
    unsigned u = __float_as_uint(f);
    u += 0x7FFF + ((u >> 16) & 1);
    return (unsigned short)(u >> 16);
}
__device__ inline float bflo(unsigned u) { return __uint_as_float(u << 16); }
__device__ inline float bfhi(unsigned u) { return __uint_as_float(u & 0xFFFF0000u); }

// ---------------------------------------------------------------------------
// 0) prep: W -> bf16 (blocks 0..15), zero partition cursors (blocks 16..35)
// ---------------------------------------------------------------------------
__global__ __launch_bounds__(256) void prep(
    const float* __restrict__ W, short* __restrict__ wbf,
    int* __restrict__ bincnt1)
{
    const int tid = threadIdx.x;
    if (blockIdx.x < 16) {
        const int i = blockIdx.x * 256 + tid;      // 4096 float4 = 128*128
        const float4 f = ((const float4*)W)[i];
        s16x4 o;
        o[0] = (short)f2bf(f.x); o[1] = (short)f2bf(f.y);
        o[2] = (short)f2bf(f.z); o[3] = (short)f2bf(f.w);
        ((s16x4*)wbf)[i] = o;
    } else {
        const int i = (blockIdx.x - 16) * 256 + tid;
        if (i < NBIN1 * NGRP * 16) bincnt1[i] = 0;  // 5120 ints
    }
}

// ---------------------------------------------------------------------------
// 1) fused: blocks [0,625) partition edges into 40 coarse bins (8 groups);
//           blocks [625,938) MFMA gemm  ybf = bf16(x @ W^T).
// ---------------------------------------------------------------------------
__global__ __launch_bounds__(256) void part_gemm(
    const int*   __restrict__ src,
    const int*   __restrict__ dst,
    const float* __restrict__ vals,
    int*         __restrict__ bincnt1,
    int2*        __restrict__ binned,
    const float* __restrict__ x,
    const short* __restrict__ wbf,
    short*       __restrict__ ybf)
{
    const int tid = threadIdx.x;
    if (blockIdx.x < PART_BLOCKS) {
        // ---------------- partition ----------------
        __shared__ int  lcnt[NBIN1], lrank[NBIN1], lstart[NBIN1 + 1], gbase[NBIN1];
        __shared__ int2 stage[1024];
        const int ebase = blockIdx.x * 1024;
        if (tid < NBIN1) { lcnt[tid] = 0; lrank[tid] = 0; }
        __syncthreads();

        const int4   s4 = ((const int4*)(src + ebase))[tid];
        const int4   d4 = ((const int4*)(dst + ebase))[tid];
        const float4 v4 = ((const float4*)(vals + ebase))[tid];
        const int   dd[4] = {d4.x, d4.y, d4.z, d4.w};
        const int   ss[4] = {s4.x, s4.y, s4.z, s4.w};
        const float vv[4] = {v4.x, v4.y, v4.z, v4.w};

        int bb[4];
        #pragma unroll
        for (int k = 0; k < 4; ++k) {
            bb[k] = dd[k] >> 8;
            atomicAdd(&lcnt[bb[k]], 1);
        }
        __syncthreads();
        if (tid == 0) {
            int run = 0;
            #pragma unroll
            for (int b = 0; b < NBIN1; ++b) { lstart[b] = run; run += lcnt[b]; }
            lstart[NBIN1] = run;
        }
        __syncthreads();
        const int g = blockIdx.x & 7;
        if (tid < NBIN1) gbase[tid] = atomicAdd(&bincnt1[(tid * NGRP + g) * 16], lcnt[tid]);
        __syncthreads();

        #pragma unroll
        for (int k = 0; k < 4; ++k) {
            const int r = atomicAdd(&lrank[bb[k]], 1);
            int2 rec;
            rec.x = (dd[k] << 16) | ss[k];     // dst<16384 (bits 16..29), src<65536
            rec.y = __float_as_int(vv[k]);
            stage[lstart[bb[k]] + r] = rec;
        }
        __syncthreads();

        // write staged, bin-sorted records; bin recovered from record bits
        #pragma unroll
        for (int k = 0; k < 4; ++k) {
            const int s = tid + k * 256;
            const int2 rec = stage[s];
            const int b = (rec.x >> 24) & 63;           // dst>>8
            const int idx = gbase[b] + (s - lstart[b]);
            if (idx < CAP1)
                binned[(size_t)(b * NGRP + g) * CAP1 + idx] = rec;
        }
        return;
    }

    // ---------------- gemm (layout per learn_hip m89/m91) ----------------
    const int gb   = blockIdx.x - PART_BLOCKS;
    const int wid  = tid >> 6;
    const int lane = tid & 63;
    const int rowbase = gb * 32 + (wid >> 1) * 16;
    if (rowbase >= N_NODES) return;
    const int colbase = (wid & 1) * 64;

    const int lr = lane & 15;
    const int kg = lane >> 4;

    bf16x8 afr[4];
    const float* xrow = x + (size_t)(rowbase + lr) * D;
    #pragma unroll
    for (int ks = 0; ks < 4; ++ks) {
        const float4 f0 = ((const float4*)(xrow + ks * 32 + kg * 8))[0];
        const float4 f1 = ((const float4*)(xrow + ks * 32 + kg * 8))[1];
        bf16x8 a;
        a[0] = (short)f2bf(f0.x); a[1] = (short)f2bf(f0.y);
        a[2] = (short)f2bf(f0.z); a[3] = (short)f2bf(f0.w);
        a[4] = (short)f2bf(f1.x); a[5] = (short)f2bf(f1.y);
        a[6] = (short)f2bf(f1.z); a[7] = (short)f2bf(f1.w);
        afr[ks] = a;
    }

    #pragma unroll
    for (int ot = 0; ot < 4; ++ot) {
        const int o = colbase + ot * 16 + lr;
        const bf16x8* wrow = (const bf16x8*)(wbf + (size_t)o * D);
        f32x4 acc = {0.f, 0.f, 0.f, 0.f};
        #pragma unroll
        for (int ks = 0; ks < 4; ++ks) {
            acc = __builtin_amdgcn_mfma_f32_16x16x32_bf16(
                      afr[ks], wrow[ks * 4 + kg], acc, 0, 0, 0);
        }
        #pragma unroll
        for (int r = 0; r < 4; ++r)
            ybf[(size_t)(rowbase + kg * 4 + r) * D + o] = (short)f2bf(acc[r]);
    }
}

// ---------------------------------------------------------------------------
// 2) aggregate2: block = one subbin (16 nodes), 1024 threads = 16 waves.
//    Reads the bin's 8 LLC-resident segments directly, filters to this
//    subbin (~1/16 kept), stages per-node in LDS (native int LDS atomics),
//    then wave w register-accumulates node w. No sort2 kernel, no f32
//    atomics anywhere.
// ---------------------------------------------------------------------------
__global__ __launch_bounds__(1024) void aggregate2(
    const short* __restrict__ ybf,
    const int*   __restrict__ bincnt1,
    const int2*  __restrict__ binned,
    const float* __restrict__ bias,
    float*       __restrict__ out)
{
    __shared__ int2 st[16][CAP_N];      // 16.6 KB
    __shared__ int  nrank[16];

    const int tid  = threadIdx.x;
    const int sub  = blockIdx.x;        // 0..624
    const int bin  = sub >> 4;          // coarse bin
    const int wid  = tid >> 6;          // 0..15 = node within subbin
    const int lane = tid & 63;

    if (tid < 16) nrank[tid] = 0;
    __syncthreads();

    // filter scan over the bin's 8 segments
    #pragma unroll
    for (int g = 0; g < NGRP; ++g) {
        const int scnt = min(bincnt1[(bin * NGRP + g) * 16], CAP1);
        const int2* seg = binned + (size_t)(bin * NGRP + g) * CAP1;
        for (int i = tid; i < scnt; i += 1024) {
            const int2 r = seg[i];
            const int d = r.x >> 16;               // dst (rec.x positive)
            if ((d >> 4) == sub) {
                const int k = atomicAdd(&nrank[d & 15], 1);
                if (k < CAP_N) st[d & 15][k] = r;
            }
        }
    }
    __syncthreads();

    // wave w accumulates node w of the subbin
    const int cnt = min(nrank[wid], CAP_N);
    const float2 bb = ((const float2*)bias)[lane];

    float2 a0 = make_float2(0.f, 0.f);
    float2 a1 = a0, a2 = a0, a3 = a0;

    int i = 0;
    for (; i + 4 <= cnt; i += 4) {
        const int2 p0 = st[wid][i + 0];
        const int2 p1 = st[wid][i + 1];
        const int2 p2 = st[wid][i + 2];
        const int2 p3 = st[wid][i + 3];
        const unsigned u0 = *(const unsigned*)(ybf + (size_t)(p0.x & 0xFFFF) * D + lane * 2);
        const unsigned u1 = *(const unsigned*)(ybf + (size_t)(p1.x & 0xFFFF) * D + lane * 2);
        const unsigned u2 = *(const unsigned*)(ybf + (size_t)(p2.x & 0xFFFF) * D + lane * 2);
        const unsigned u3 = *(const unsigned*)(ybf + (size_t)(p3.x & 0xFFFF) * D + lane * 2);
        const float v0 = __int_as_float(p0.y), v1 = __int_as_float(p1.y);
        const float v2 = __int_as_float(p2.y), v3 = __int_as_float(p3.y);
        a0.x = fmaf(v0, bflo(u0), a0.x);  a0.y = fmaf(v0, bfhi(u0), a0.y);
        a1.x = fmaf(v1, bflo(u1), a1.x);  a1.y = fmaf(v1, bfhi(u1), a1.y);
        a2.x = fmaf(v2, bflo(u2), a2.x);  a2.y = fmaf(v2, bfhi(u2), a2.y);
        a3.x = fmaf(v3, bflo(u3), a3.x);  a3.y = fmaf(v3, bfhi(u3), a3.y);
    }
    for (; i < cnt; ++i) {
        const int2 p = st[wid][i];
        const unsigned u = *(const unsigned*)(ybf + (size_t)(p.x & 0xFFFF) * D + lane * 2);
        const float v = __int_as_float(p.y);
        a0.x = fmaf(v, bflo(u), a0.x);
        a0.y = fmaf(v, bfhi(u), a0.y);
    }

    float2 r;
    r.x = bb.x + (a0.x + a1.x) + (a2.x + a3.x);
    r.y = bb.y + (a0.y + a1.y) + (a2.y + a3.y);
    ((float2*)(out + (size_t)(sub * 16 + wid) * D))[lane] = r;
}

// ---------------------------------------------------------------------------
extern "C" void kernel_launch(void* const* d_in, const int* in_sizes, int n_in,
                              void* d_out, int out_size, void* d_ws, size_t ws_size,
                              hipStream_t stream)
{
    const float* x    = (const float*)d_in[0];
    const int*   src  = (const int*)d_in[1];
    const int*   dst  = (const int*)d_in[2];
    const float* vals = (const float*)d_in[3];
    const float* W    = (const float*)d_in[4];
    const float* b    = (const float*)d_in[5];
    float*       out  = (float*)d_out;

    char* ws = (char*)d_ws;
    int*   bincnt1 = (int*)(ws + WS_BC1);
    short* wbf     = (short*)(ws + WS_WBF);
    int2*  binned  = (int2*)(ws + WS_BINNED);
    short* ybf     = (short*)(ws + WS_YBF);

    prep<<<36, 256, 0, stream>>>(W, wbf, bincnt1);
    part_gemm<<<PART_BLOCKS + GEMM_BLOCKS, 256, 0, stream>>>(
        src, dst, vals, bincnt1, binned, x, wbf, ybf);
    aggregate2<<<NSUB, 1024, 0, stream>>>(ybf, bincnt1, binned, b, out);
}

// Round 14
// 102.954 us; speedup vs baseline: 1.0678x; 1.0678x over previous
//
#include <hip/hip_runtime.h>

constexpr int N_NODES = 10000;
constexpr int N_EDGES = 640000;
constexpr int D       = 128;    // D_IN == D_OUT == 128
constexpr int NBIN1   = 40;     // coarse bin = dst >> 8  (256 nodes)
constexpr int NGRP    = 8;      // cursor groups (blockIdx & 7)
constexpr int CAP1    = 2432;   // per (bin,grp) segment cap: E=2022, +9 sigma
constexpr int NSUB    = 625;    // subbin = dst >> 4  (16 nodes)
constexpr int CAP2    = 1280;   // per-subbin cap: E=1024, +8 sigma
constexpr int GEMM_BLOCKS = 313;
constexpr int PART_BLOCKS = 625;
constexpr int SORT_BLOCKS = NBIN1 * NGRP;   // 320

// workspace layout (bytes)
constexpr size_t WS_BC1    = 0;         // int[40*8*16] = 20480
constexpr size_t WS_SBC    = 20480;     // int[640]
constexpr size_t WS_WBF    = 24576;     // bf16[128*128]
constexpr size_t WS_BINNED = 65536;     // int2[40*8*2432]
constexpr size_t WS_SORTED = 6291456;   // int2[625*1280]
constexpr size_t WS_YBF    = 12691456;  // bf16[10000*128]

typedef __attribute__((ext_vector_type(8))) short bf16x8;
typedef __attribute__((ext_vector_type(4))) short s16x4;
typedef __attribute__((ext_vector_type(4))) float f32x4;

__device__ inline unsigned short f2bf(float f) {   // round-to-nearest-even
    unsigned u = __float_as_uint(f);
    u += 0x7FFF + ((u >> 16) & 1);
    return (unsigned short)(u >> 16);
}
__device__ inline float bflo(unsigned u) { return __uint_as_float(u << 16); }
__device__ inline float bfhi(unsigned u) { return __uint_as_float(u & 0xFFFF0000u); }

// ---------------------------------------------------------------------------
// 0) prep: W -> bf16 (blocks 0..15), zero cursors (blocks 16..)
// ---------------------------------------------------------------------------
__global__ __launch_bounds__(256) void prep(
    const float* __restrict__ W, short* __restrict__ wbf,
    int* __restrict__ bincnt1, int* __restrict__ sbcnt)
{
    const int tid = threadIdx.x;
    if (blockIdx.x < 16) {
        const int i = blockIdx.x * 256 + tid;      // 4096 float4 = 128*128
        const float4 f = ((const float4*)W)[i];
        s16x4 o;
        o[0] = (short)f2bf(f.x); o[1] = (short)f2bf(f.y);
        o[2] = (short)f2bf(f.z); o[3] = (short)f2bf(f.w);
        ((s16x4*)wbf)[i] = o;
    } else {
        const int i = (blockIdx.x - 16) * 256 + tid;
        if (i < NBIN1 * NGRP * 16) bincnt1[i] = 0;  // 5120
        if (i < NSUB + 15)         sbcnt[i]   = 0;  // 640
    }
}

// ---------------------------------------------------------------------------
// 1) fused: blocks [0,625) partition edges into 40 coarse bins (8 groups);
//           blocks [625, 938) MFMA gemm  ybf = bf16(x @ W^T).
// ---------------------------------------------------------------------------
__global__ __launch_bounds__(256) void part_gemm(
    const int*   __restrict__ src,
    const int*   __restrict__ dst,
    const float* __restrict__ vals,
    int*         __restrict__ bincnt1,
    int2*        __restrict__ binned,
    const float* __restrict__ x,
    const short* __restrict__ wbf,
    short*       __restrict__ ybf)
{
    const int tid = threadIdx.x;
    if (blockIdx.x < PART_BLOCKS) {
        // ---------------- partition ----------------
        __shared__ int  lcnt[NBIN1], lrank[NBIN1], lstart[NBIN1 + 1], gbase[NBIN1];
        __shared__ int2 stage[1024];
        const int ebase = blockIdx.x * 1024;
        if (tid < NBIN1) { lcnt[tid] = 0; lrank[tid] = 0; }
        __syncthreads();

        const int4   s4 = ((const int4*)(src + ebase))[tid];
        const int4   d4 = ((const int4*)(dst + ebase))[tid];
        const float4 v4 = ((const float4*)(vals + ebase))[tid];
        const int   dd[4] = {d4.x, d4.y, d4.z, d4.w};
        const int   ss[4] = {s4.x, s4.y, s4.z, s4.w};
        const float vv[4] = {v4.x, v4.y, v4.z, v4.w};

        int bb[4];
        #pragma unroll
        for (int k = 0; k < 4; ++k) {
            bb[k] = dd[k] >> 8;
            atomicAdd(&lcnt[bb[k]], 1);
        }
        __syncthreads();
        if (tid == 0) {
            int run = 0;
            #pragma unroll
            for (int b = 0; b < NBIN1; ++b) { lstart[b] = run; run += lcnt[b]; }
            lstart[NBIN1] = run;
        }
        __syncthreads();
        const int g = blockIdx.x & 7;
        if (tid < NBIN1) gbase[tid] = atomicAdd(&bincnt1[(tid * NGRP + g) * 16], lcnt[tid]);
        __syncthreads();

        #pragma unroll
        for (int k = 0; k < 4; ++k) {
            const int r = atomicAdd(&lrank[bb[k]], 1);
            int2 rec;
            rec.x = (dd[k] << 16) | ss[k];     // dst<16384, src<65536
            rec.y = __float_as_int(vv[k]);
            stage[lstart[bb[k]] + r] = rec;
        }
        __syncthreads();

        #pragma unroll
        for (int k = 0; k < 4; ++k) {
            const int s = tid + k * 256;
            const int2 rec = stage[s];
            const int b = (rec.x >> 24) & 63;           // dst>>8
            const int idx = gbase[b] + (s - lstart[b]);
            if (idx < CAP1)
                binned[(size_t)(b * NGRP + g) * CAP1 + idx] = rec;
        }
        return;
    }

    // ---------------- gemm (layout per learn_hip m89/m91) ----------------
    const int gb   = blockIdx.x - PART_BLOCKS;
    const int wid  = tid >> 6;
    const int lane = tid & 63;
    const int rowbase = gb * 32 + (wid >> 1) * 16;
    if (rowbase >= N_NODES) return;
    const int colbase = (wid & 1) * 64;

    const int lr = lane & 15;
    const int kg = lane >> 4;

    bf16x8 afr[4];
    const float* xrow = x + (size_t)(rowbase + lr) * D;
    #pragma unroll
    for (int ks = 0; ks < 4; ++ks) {
        const float4 f0 = ((const float4*)(xrow + ks * 32 + kg * 8))[0];
        const float4 f1 = ((const float4*)(xrow + ks * 32 + kg * 8))[1];
        bf16x8 a;
        a[0] = (short)f2bf(f0.x); a[1] = (short)f2bf(f0.y);
        a[2] = (short)f2bf(f0.z); a[3] = (short)f2bf(f0.w);
        a[4] = (short)f2bf(f1.x); a[5] = (short)f2bf(f1.y);
        a[6] = (short)f2bf(f1.z); a[7] = (short)f2bf(f1.w);
        afr[ks] = a;
    }

    #pragma unroll
    for (int ot = 0; ot < 4; ++ot) {
        const int o = colbase + ot * 16 + lr;
        const bf16x8* wrow = (const bf16x8*)(wbf + (size_t)o * D);
        f32x4 acc = {0.f, 0.f, 0.f, 0.f};
        #pragma unroll
        for (int ks = 0; ks < 4; ++ks) {
            acc = __builtin_amdgcn_mfma_f32_16x16x32_bf16(
                      afr[ks], wrow[ks * 4 + kg], acc, 0, 0, 0);
        }
        #pragma unroll
        for (int r = 0; r < 4; ++r)
            ybf[(size_t)(rowbase + kg * 4 + r) * D + o] = (short)f2bf(acc[r]);
    }
}

// ---------------------------------------------------------------------------
// 2) sort2: block = one (bin,grp) segment (~2k records) -> group by subbin
// ---------------------------------------------------------------------------
__global__ __launch_bounds__(256) void sort2(
    const int*  __restrict__ bincnt1,
    const int2* __restrict__ binned,
    int*        __restrict__ sbcnt,
    int2*       __restrict__ sorted)
{
    __shared__ int2 st1[CAP1];
    __shared__ int2 st2[CAP1];
    __shared__ int  scnt[16], srank[16], sstart[17], sgbase[16];

    const int tid = threadIdx.x;
    const int seg = blockIdx.x;            // 0..319
    const int bin = seg >> 3;
    const int cnt = min(bincnt1[seg * 16], CAP1);

    if (tid < 16) { scnt[tid] = 0; srank[tid] = 0; }
    __syncthreads();

    const int2* in = binned + (size_t)seg * CAP1;
    for (int i = tid; i < cnt; i += 256) {
        const int2 rec = in[i];
        st1[i] = rec;
        atomicAdd(&scnt[(rec.x >> 20) & 15], 1);
    }
    __syncthreads();
    if (tid == 0) {
        int run = 0;
        #pragma unroll
        for (int s = 0; s < 16; ++s) { sstart[s] = run; run += scnt[s]; }
        sstart[16] = run;
    }
    __syncthreads();
    if (tid < 16) sgbase[tid] = atomicAdd(&sbcnt[bin * 16 + tid], scnt[tid]);
    __syncthreads();

    for (int i = tid; i < cnt; i += 256) {
        const int2 rec = st1[i];
        const int sb = (rec.x >> 20) & 15;
        const int r  = atomicAdd(&srank[sb], 1);
        st2[sstart[sb] + r] = rec;
    }
    __syncthreads();

    for (int i = tid; i < cnt; i += 256) {
        int sb = 0;
        #pragma unroll
        for (int q = 1; q < 16; ++q) sb += (i >= sstart[q]);
        const int gidx = sgbase[sb] + (i - sstart[sb]);
        if (gidx < CAP2)
            sorted[(size_t)(bin * 16 + sb) * CAP2 + gidx] = st2[i];
    }
}

// ---------------------------------------------------------------------------
// 3) aggregate: block = one subbin (16 nodes), 1024 threads = 16 waves.
//    In-LDS node-sort (native int LDS atomics), then wave w register-
//    accumulates node w (serial depth 64/8 = 8 rounds, 8 row-loads in
//    flight). No f32 atomics of any scope.
// ---------------------------------------------------------------------------
__global__ __launch_bounds__(1024) void aggregate(
    const short* __restrict__ ybf,
    const int*   __restrict__ sbcnt,
    const int2*  __restrict__ sorted,
    const float* __restrict__ bias,
    float*       __restrict__ out)
{
    __shared__ int2 st[CAP2];       // 10 KB
    __shared__ int2 st2[CAP2];      // 10 KB
    __shared__ int  ncnt[16], nrank[16], nstart[17];

    const int tid  = threadIdx.x;
    const int sub  = blockIdx.x;    // 0..624
    const int wid  = tid >> 6;      // 0..15 = node within subbin
    const int lane = tid & 63;

    if (tid < 16) { ncnt[tid] = 0; nrank[tid] = 0; }
    __syncthreads();

    const int cnt = min(sbcnt[sub], CAP2);
    const int2* recs = sorted + (size_t)sub * CAP2;
    for (int i = tid; i < cnt; i += 1024) {
        const int2 r = recs[i];
        st[i] = r;
        atomicAdd(&ncnt[(r.x >> 16) & 15], 1);      // int LDS atomic: native
    }
    __syncthreads();
    if (tid == 0) {
        int run = 0;
        #pragma unroll
        for (int s = 0; s < 16; ++s) { nstart[s] = run; run += ncnt[s]; }
        nstart[16] = run;
    }
    __syncthreads();
    for (int i = tid; i < cnt; i += 1024) {
        const int2 r = st[i];
        const int d = (r.x >> 16) & 15;
        const int k = atomicAdd(&nrank[d], 1);      // int LDS atomic: native
        st2[nstart[d] + k] = r;
    }
    __syncthreads();

    // wave w accumulates node w: unroll 8 -> 8 independent ybf row loads
    const int beg = nstart[wid];
    const int end = nstart[wid + 1];
    const float2 bb = ((const float2*)bias)[lane];

    float2 a0 = make_float2(0.f, 0.f);
    float2 a1 = a0, a2 = a0, a3 = a0, a4 = a0, a5 = a0, a6 = a0, a7 = a0;

    int i = beg;
    for (; i + 8 <= end; i += 8) {
        const int2 p0 = st2[i + 0];
        const int2 p1 = st2[i + 1];
        const int2 p2 = st2[i + 2];
        const int2 p3 = st2[i + 3];
        const int2 p4 = st2[i + 4];
        const int2 p5 = st2[i + 5];
        const int2 p6 = st2[i + 6];
        const int2 p7 = st2[i + 7];
        const unsigned u0 = *(const unsigned*)(ybf + (size_t)(p0.x & 0xFFFF) * D + lane * 2);
        const unsigned u1 = *(const unsigned*)(ybf + (size_t)(p1.x & 0xFFFF) * D + lane * 2);
        const unsigned u2 = *(const unsigned*)(ybf + (size_t)(p2.x & 0xFFFF) * D + lane * 2);
        const unsigned u3 = *(const unsigned*)(ybf + (size_t)(p3.x & 0xFFFF) * D + lane * 2);
        const unsigned u4 = *(const unsigned*)(ybf + (size_t)(p4.x & 0xFFFF) * D + lane * 2);
        const unsigned u5 = *(const unsigned*)(ybf + (size_t)(p5.x & 0xFFFF) * D + lane * 2);
        const unsigned u6 = *(const unsigned*)(ybf + (size_t)(p6.x & 0xFFFF) * D + lane * 2);
        const unsigned u7 = *(const unsigned*)(ybf + (size_t)(p7.x & 0xFFFF) * D + lane * 2);
        const float v0 = __int_as_float(p0.y), v1 = __int_as_float(p1.y);
        const float v2 = __int_as_float(p2.y), v3 = __int_as_float(p3.y);
        const float v4 = __int_as_float(p4.y), v5 = __int_as_float(p5.y);
        const float v6 = __int_as_float(p6.y), v7 = __int_as_float(p7.y);
        a0.x = fmaf(v0, bflo(u0), a0.x);  a0.y = fmaf(v0, bfhi(u0), a0.y);
        a1.x = fmaf(v1, bflo(u1), a1.x);  a1.y = fmaf(v1, bfhi(u1), a1.y);
        a2.x = fmaf(v2, bflo(u2), a2.x);  a2.y = fmaf(v2, bfhi(u2), a2.y);
        a3.x = fmaf(v3, bflo(u3), a3.x);  a3.y = fmaf(v3, bfhi(u3), a3.y);
        a4.x = fmaf(v4, bflo(u4), a4.x);  a4.y = fmaf(v4, bfhi(u4), a4.y);
        a5.x = fmaf(v5, bflo(u5), a5.x);  a5.y = fmaf(v5, bfhi(u5), a5.y);
        a6.x = fmaf(v6, bflo(u6), a6.x);  a6.y = fmaf(v6, bfhi(u6), a6.y);
        a7.x = fmaf(v7, bflo(u7), a7.x);  a7.y = fmaf(v7, bfhi(u7), a7.y);
    }
    for (; i < end; ++i) {
        const int2 p = st2[i];
        const unsigned u = *(const unsigned*)(ybf + (size_t)(p.x & 0xFFFF) * D + lane * 2);
        const float v = __int_as_float(p.y);
        a0.x = fmaf(v, bflo(u), a0.x);
        a0.y = fmaf(v, bfhi(u), a0.y);
    }

    float2 r;
    r.x = bb.x + ((a0.x + a1.x) + (a2.x + a3.x)) + ((a4.x + a5.x) + (a6.x + a7.x));
    r.y = bb.y + ((a0.y + a1.y) + (a2.y + a3.y)) + ((a4.y + a5.y) + (a6.y + a7.y));
    ((float2*)(out + (size_t)(sub * 16 + wid) * D))[lane] = r;
}

// ---------------------------------------------------------------------------
extern "C" void kernel_launch(void* const* d_in, const int* in_sizes, int n_in,
                              void* d_out, int out_size, void* d_ws, size_t ws_size,
                              hipStream_t stream)
{
    const float* x    = (const float*)d_in[0];
    const int*   src  = (const int*)d_in[1];
    const int*   dst  = (const int*)d_in[2];
    const float* vals = (const float*)d_in[3];
    const float* W    = (const float*)d_in[4];
    const float* b    = (const float*)d_in[5];
    float*       out  = (float*)d_out;

    char* ws = (char*)d_ws;
    int*   bincnt1 = (int*)(ws + WS_BC1);
    int*   sbcnt   = (int*)(ws + WS_SBC);
    short* wbf     = (short*)(ws + WS_WBF);
    int2*  binned  = (int2*)(ws + WS_BINNED);
    int2*  sorted  = (int2*)(ws + WS_SORTED);
    short* ybf     = (short*)(ws + WS_YBF);

    prep<<<39, 256, 0, stream>>>(W, wbf, bincnt1, sbcnt);
    part_gemm<<<PART_BLOCKS + GEMM_BLOCKS, 256, 0, stream>>>(
        src, dst, vals, bincnt1, binned, x, wbf, ybf);
    sort2<<<SORT_BLOCKS, 256, 0, stream>>>(bincnt1, binned, sbcnt, sorted);
    aggregate<<<NSUB, 1024, 0, stream>>>(ybf, sbcnt, sorted, b, out);
}